// Round 8
// baseline (223.567 us; speedup 1.0000x reference)
//
#include <hip/hip_runtime.h>
#include <hip/hip_bf16.h>

#define N_ROWS 8192
#define D_DIM  4096
#define E_DIM  64
#define BR     32                 // rows per block
#define HALFK  2048               // K elems per wave-half
#define BK     256                // fp32 K elems per staged chunk
#define NCH    (HALFK / BK)       // 8 chunks per half
#define NSTEP  (BK / 32)          // 8 K32-steps per chunk

typedef __attribute__((ext_vector_type(8))) short  short8;
typedef __attribute__((ext_vector_type(4))) float  floatx4;
typedef __attribute__((ext_vector_type(8))) float  float8;

// Split an fp32 vector into hi (RNE bf16) + lo (chopped bf16 of remainder).
// Bitwise-identical to the verified kernel -> identical numerics.
__device__ inline void cvt_split(const float8& f, short8& hi, short8& lo) {
#pragma unroll
  for (int j = 0; j < 8; ++j) {
    float x = f[j];
    unsigned int u  = __builtin_bit_cast(unsigned int, x);
    unsigned int rh = (u + 0x7FFFu + ((u >> 16) & 1u)) >> 16;  // RNE to bf16
    hi[j] = (short)rh;
    float hf = __builtin_bit_cast(float, rh << 16);
    float lf = x - hf;
    unsigned int ul = __builtin_bit_cast(unsigned int, lf);
    lo[j] = (short)(ul >> 16);                                  // chop
  }
}

// ---------------------------------------------------------------------------
// Prep kernel: convert W fp32 [64][4096] -> d_ws split-bf16 in FRAGMENT order.
// For K32-step s (0..127), expert tile e (0..3), plane p (hi/lo), lane l:
//   16B fragment = W rows e*16+(l&15), k = s*32+(l>>4)*8 .. +7
//   stored at ws + (s*8 + e*2 + p)*1024 + l*16          (total 1 MB)
// ---------------------------------------------------------------------------
__global__ __launch_bounds__(512) void prep_w(const void* __restrict__ xv,
                                              const void* __restrict__ wv,
                                              void* __restrict__ ws) {
  __shared__ int sflag;
  const int tid = threadIdx.x;
  if (tid < 64) {   // dtype probe (skip conversion if inputs are bf16)
    unsigned int v = ((const unsigned int*)xv)[(size_t)tid * 997];
    unsigned int e = (v >> 7) & 0xFFu;
    unsigned long long m = __ballot(e >= 100u && e <= 140u);
    if (tid == 0) sflag = (__popcll(m) > 32) ? 1 : 0;
  }
  __syncthreads();
  if (sflag) return;
  const int t    = blockIdx.x * 512 + tid;   // 64 blocks x 512 = 32768
  const int lane = t & 63;
  const int idx  = t >> 6;                    // s*4 + e
  const int s    = idx >> 2;
  const int e    = idx & 3;
  const int row  = e * 16 + (lane & 15);
  const int col  = s * 32 + (lane >> 4) * 8;
  float8 f = *(const float8*)((const float*)wv + (size_t)row * D_DIM + col);
  short8 h, l;
  cvt_split(f, h, l);
  char* d = (char*)ws + (size_t)idx * 2048 + lane * 16;
  *(short8*)d          = h;
  *(short8*)(d + 1024) = l;
}

// ---------------------------------------------------------------------------
// Main fused router: 256 blocks x 512 threads. Block = 32 rows, all 64
// experts, K SPLIT ACROSS WAVES.
// 8 waves: wave w -> (expert tile e = w&3, K-half h = w>>2). Each wave runs
// the round-7 pipeline on its 2048-wide K-half (8 chunks), with an
// independent double-buffered LDS x-pipeline per half. Partial logits go to
// lg[h]; epilogue sums the two planes.
//
// Round-8 theory: round-7 was concurrency-starved (1 wave/SIMD, Occ 8.4%,
// all pipes <12%) — latency fully exposed. K-split doubles waves/SIMD to 2
// and halves each wave's serial chain + barrier count, with unchanged B
// traffic (256 MB) and non-redundant x conversion.
//  * B frags in NAMED regs (rule #20), prefetched one chunk ahead.
//  * barrier = "s_waitcnt lgkmcnt(0); s_barrier" (LDS-visibility only;
//    global prefetches stay in flight across barriers).
//  * x staging: reg-staged split-bf16, slot^row XOR swizzle on write+read.
// ---------------------------------------------------------------------------
__global__ __launch_bounds__(512, 2) void router_kernel(
    const void* __restrict__ xv, const void* __restrict__ wv,
    const void* __restrict__ bv, const void* __restrict__ wsv,
    float* __restrict__ out) {
  __shared__ __align__(16) char sm[2][2][32768];  // [half][buf]: xh 16K|xl 16K
  __shared__ float lg[2][BR][E_DIM + 4];          // [half][row][expert]
  __shared__ int   sflag;

  const int tid = threadIdx.x;

  if (tid < 64) {   // dtype probe
    unsigned int v = ((const unsigned int*)xv)[(size_t)tid * 997];
    unsigned int e = (v >> 7) & 0xFFu;
    unsigned long long m = __ballot(e >= 100u && e <= 140u);
    if (tid == 0) sflag = (__popcll(m) > 32) ? 1 : 0;
  }
  __syncthreads();
  const int isbf = sflag;

  const int wave = tid >> 6;            // 0..7
  const int h    = wave >> 2;           // K-half 0/1
  const int et   = wave & 3;            // expert tile 0..3
  const int lane = tid & 63;
  const int lm   = lane & 15;           // A: row-in-subtile  B: expert-in-tile
  const int t4   = lane >> 4;           // k sub-slot within 32-wide K step
  const int r0   = blockIdx.x * BR;

  floatx4 acc0 = {0.f, 0.f, 0.f, 0.f};  // rows 0..15   (this K-half)
  floatx4 acc1 = {0.f, 0.f, 0.f, 0.f};  // rows 16..31  (this K-half)

  if (!isbf) {
    // staging geometry: 256 threads per half; thread -> 32 floats of one row
    const int stid = tid & 255;
    const int srow = stid >> 3;         // 0..31
    const int grp  = stid & 7;          // 32-float col group
    const float* xg = (const float*)xv +
        (size_t)(r0 + srow) * D_DIM + h * HALFK + grp * 32;
    const int ws0 = srow * 512 + (((grp * 4 + 0) ^ (srow & 7)) << 4);
    const int ws1 = srow * 512 + (((grp * 4 + 1) ^ (srow & 7)) << 4);
    const int ws2 = srow * 512 + (((grp * 4 + 2) ^ (srow & 7)) << 4);
    const int ws3 = srow * 512 + (((grp * 4 + 3) ^ (srow & 7)) << 4);
    // B fragment base: K32-step s = h*64 + i*8 + kk; frag at
    // wsv + s*8192 + et*2048 + p*1024 + lane*16
    const char* wb = (const char*)wsv + (size_t)h * 524288 +
                     (size_t)et * 2048 + lane * 16;
    // A read bases: sub0 row = lm, sub1 row = 16+lm; (16+lm)&7 == lm&7
    const int ra  = lm * 512;
    const int axr = lm & 7;

    // named B-fragment registers (NO arrays -> stay in VGPRs)
    short8 bh0, bh1, bh2, bh3, bh4, bh5, bh6, bh7;
    short8 bl0, bl1, bl2, bl3, bl4, bl5, bl6, bl7;

#define LDB(K, BASE)                                                       \
    bh##K = *(const short8*)((BASE) + (size_t)(K) * 8192);                 \
    bl##K = *(const short8*)((BASE) + (size_t)(K) * 8192 + 1024);

#define STAGE(DST, F0, F1, F2, F3)                                         \
    {                                                                      \
      short8 hh, ll;                                                       \
      cvt_split(F0, hh, ll); *(short8*)((DST) + ws0) = hh;                 \
                             *(short8*)((DST) + 16384 + ws0) = ll;         \
      cvt_split(F1, hh, ll); *(short8*)((DST) + ws1) = hh;                 \
                             *(short8*)((DST) + 16384 + ws1) = ll;         \
      cvt_split(F2, hh, ll); *(short8*)((DST) + ws2) = hh;                 \
                             *(short8*)((DST) + 16384 + ws2) = ll;         \
      cvt_split(F3, hh, ll); *(short8*)((DST) + ws3) = hh;                 \
                             *(short8*)((DST) + 16384 + ws3) = ll;         \
    }

    // prologue: B frags for chunk 0 of this half, x chunk 0 staged to LDS
    LDB(0, wb) LDB(1, wb) LDB(2, wb) LDB(3, wb)
    LDB(4, wb) LDB(5, wb) LDB(6, wb) LDB(7, wb)
    {
      float8 f0 = *(const float8*)xg;
      float8 f1 = *(const float8*)(xg + 8);
      float8 f2 = *(const float8*)(xg + 16);
      float8 f3 = *(const float8*)(xg + 24);
      STAGE(sm[h][0], f0, f1, f2, f3)
    }
    asm volatile("s_waitcnt lgkmcnt(0)\n\ts_barrier" ::: "memory");

    for (int i = 0; i < NCH; ++i) {
      // 1) issue next-chunk x loads (consumed at step 3)
      float8 f0, f1, f2, f3;
      if (i + 1 < NCH) {
        const int o = (i + 1) * BK;
        f0 = *(const float8*)(xg + o);
        f1 = *(const float8*)(xg + o + 8);
        f2 = *(const float8*)(xg + o + 16);
        f3 = *(const float8*)(xg + o + 24);
      }
      // 2) compute chunk i; each step reloads its B frag for chunk i+1
      const char* s   = sm[h][i & 1];
      const char* wbn = wb + (size_t)((i + 1 < NCH) ? i + 1 : i) * (NSTEP * 8192);

#define STEP(K)                                                            \
    {                                                                      \
      const int sa = ((((K) << 2) + t4) ^ axr) << 4;                       \
      short8 ah0 = *(const short8*)(s + ra + sa);                          \
      short8 al0 = *(const short8*)(s + 16384 + ra + sa);                  \
      short8 ah1 = *(const short8*)(s + 8192 + ra + sa);                   \
      short8 al1 = *(const short8*)(s + 24576 + ra + sa);                  \
      acc0 = __builtin_amdgcn_mfma_f32_16x16x32_bf16(ah0, bh##K, acc0, 0, 0, 0); \
      acc0 = __builtin_amdgcn_mfma_f32_16x16x32_bf16(ah0, bl##K, acc0, 0, 0, 0); \
      acc0 = __builtin_amdgcn_mfma_f32_16x16x32_bf16(al0, bh##K, acc0, 0, 0, 0); \
      acc1 = __builtin_amdgcn_mfma_f32_16x16x32_bf16(ah1, bh##K, acc1, 0, 0, 0); \
      acc1 = __builtin_amdgcn_mfma_f32_16x16x32_bf16(ah1, bl##K, acc1, 0, 0, 0); \
      acc1 = __builtin_amdgcn_mfma_f32_16x16x32_bf16(al1, bh##K, acc1, 0, 0, 0); \
      LDB(K, wbn)                                                          \
    }

      STEP(0) STEP(1) STEP(2) STEP(3)
      STEP(4) STEP(5) STEP(6) STEP(7)

      // 3) convert + write next x chunk into the other buffer
      if (i + 1 < NCH) {
        STAGE(sm[h][(i + 1) & 1], f0, f1, f2, f3)
      }
      // barrier with LDS-drain only: global prefetches stay in flight
      asm volatile("s_waitcnt lgkmcnt(0)\n\ts_barrier" ::: "memory");
    }
#undef STEP
#undef STAGE
#undef LDB
  } else {
    // bf16 fallback (unexercised; register-direct, no d_ws dependency)
    const short* xp0 = (const short*)xv + (size_t)(r0 + lm) * D_DIM +
                       h * HALFK + t4 * 8;
    const short* xp1 = xp0 + (size_t)16 * D_DIM;
    const short* wp  = (const short*)wv + (size_t)(et * 16 + lm) * D_DIM +
                       h * HALFK + t4 * 8;
    for (int k = 0; k < HALFK; k += 32) {
      short8 a0 = *(const short8*)(xp0 + k);
      short8 a1 = *(const short8*)(xp1 + k);
      short8 b0 = *(const short8*)(wp + k);
      acc0 = __builtin_amdgcn_mfma_f32_16x16x32_bf16(a0, b0, acc0, 0, 0, 0);
      acc1 = __builtin_amdgcn_mfma_f32_16x16x32_bf16(a1, b0, acc1, 0, 0, 0);
    }
  }

  // C/D layout (m89-verified): col = lane&15 (expert), row = (lane>>4)*4 + reg
  {
    const int col   = et * 16 + lm;
    const int rbase = t4 << 2;
#pragma unroll
    for (int r = 0; r < 4; ++r) {
      lg[h][rbase + r][col]      = acc0[r];
      lg[h][16 + rbase + r][col] = acc1[r];
    }
  }
  __syncthreads();

  if (tid < BR) {
    const int row = tid;
    float m1 = -3.4e38f, m2 = -3.4e38f;
    int   i1 = 0, i2 = 0;
    for (int e = 0; e < E_DIM; ++e) {
      float be = isbf ? __bfloat162float(((const __hip_bfloat16*)bv)[e])
                      : ((const float*)bv)[e];
      float l = lg[0][row][e] + lg[1][row][e] + be;
      if (l > m1)      { m2 = m1; i2 = i1; m1 = l; i1 = e; }
      else if (l > m2) { m2 = l;  i2 = e; }
    }
    float s = 0.f;
    for (int e = 0; e < E_DIM; ++e) {
      float be = isbf ? __bfloat162float(((const __hip_bfloat16*)bv)[e])
                      : ((const float*)bv)[e];
      s += expf(lg[0][row][e] + lg[1][row][e] + be - m1);
    }
    const int gr = r0 + row;
    // outputs concatenated flat: [N*2 indices][N*2 weights], all as float32
    out[2 * gr]                  = (float)i1;
    out[2 * gr + 1]              = (float)i2;
    out[2 * N_ROWS + 2 * gr]     = 1.0f / s;                 // exp(m1-m1)/s
    out[2 * N_ROWS + 2 * gr + 1] = expf(m2 - m1) / s;
  }
}

extern "C" void kernel_launch(void* const* d_in, const int* in_sizes, int n_in,
                              void* d_out, int out_size, void* d_ws, size_t ws_size,
                              hipStream_t stream) {
  (void)in_sizes; (void)n_in; (void)out_size; (void)ws_size;
  // prep_w writes 1 MB of fragment-ordered split-bf16 W into d_ws;
  // same-stream ordering guarantees completion before router_kernel.
  prep_w<<<dim3(64), dim3(512), 0, stream>>>(d_in[0], d_in[1], d_ws);
  router_kernel<<<dim3(N_ROWS / BR), dim3(512), 0, stream>>>(
      d_in[0], d_in[1], d_in[2], d_ws, (float*)d_out);
}

// Round 9
// 219.328 us; speedup vs baseline: 1.0193x; 1.0193x over previous
//
#include <hip/hip_runtime.h>
#include <hip/hip_bf16.h>

#define N_ROWS 8192
#define D_DIM  4096
#define E_DIM  64
#define BR     16                 // rows per block
#define BK     256                // fp32 K elems per staged chunk
#define NCH    (D_DIM / BK)       // 16 chunks
#define NSTEP  (BK / 32)          // 8 K32-steps per chunk

typedef __attribute__((ext_vector_type(8))) short  short8;
typedef __attribute__((ext_vector_type(4))) float  floatx4;
typedef __attribute__((ext_vector_type(8))) float  float8;

// async global->LDS, 16B per lane; LDS dest is wave-uniform base + lane*16
__device__ inline void gload16(const void* g, void* l) {
  __builtin_amdgcn_global_load_lds(
      (const __attribute__((address_space(1))) void*)g,
      (__attribute__((address_space(3))) void*)l, 16, 0, 0);
}

// Split an fp32 vector into hi (RNE bf16) + lo (chopped bf16 of remainder).
// Bitwise-identical math to the verified kernel -> identical numerics.
__device__ inline void cvt_split(const float8& f, short8& hi, short8& lo) {
#pragma unroll
  for (int j = 0; j < 8; ++j) {
    float x = f[j];
    unsigned int u  = __builtin_bit_cast(unsigned int, x);
    unsigned int rh = (u + 0x7FFFu + ((u >> 16) & 1u)) >> 16;  // RNE to bf16
    hi[j] = (short)rh;
    float hf = __builtin_bit_cast(float, rh << 16);
    float lf = x - hf;
    unsigned int ul = __builtin_bit_cast(unsigned int, lf);
    lo[j] = (short)(ul >> 16);                                  // chop
  }
}

// ---------------------------------------------------------------------------
// Prep kernel: convert W fp32 [64][4096] -> d_ws split-bf16 in FRAGMENT order.
// For K32-step s (0..127), expert tile e (0..3), plane p (hi/lo), lane l:
//   16B fragment = W rows e*16+(l&15), k = s*32+(l>>4)*8 .. +7
//   stored at ws + (s*8 + e*2 + p)*1024 + l*16          (total 1 MB)
// ---------------------------------------------------------------------------
__global__ __launch_bounds__(512) void prep_w(const void* __restrict__ xv,
                                              const void* __restrict__ wv,
                                              void* __restrict__ ws) {
  __shared__ int sflag;
  const int tid = threadIdx.x;
  if (tid < 64) {   // dtype probe (skip conversion if inputs are bf16)
    unsigned int v = ((const unsigned int*)xv)[(size_t)tid * 997];
    unsigned int e = (v >> 7) & 0xFFu;
    unsigned long long m = __ballot(e >= 100u && e <= 140u);
    if (tid == 0) sflag = (__popcll(m) > 32) ? 1 : 0;
  }
  __syncthreads();
  if (sflag) return;
  const int t    = blockIdx.x * 512 + tid;   // 64 blocks x 512 = 32768
  const int lane = t & 63;
  const int idx  = t >> 6;                    // s*4 + e
  const int s    = idx >> 2;
  const int e    = idx & 3;
  const int row  = e * 16 + (lane & 15);
  const int col  = s * 32 + (lane >> 4) * 8;
  float8 f = *(const float8*)((const float*)wv + (size_t)row * D_DIM + col);
  short8 h, l;
  cvt_split(f, h, l);
  char* d = (char*)ws + (size_t)idx * 2048 + lane * 16;
  *(short8*)d          = h;
  *(short8*)(d + 1024) = l;
}

// ---------------------------------------------------------------------------
// Main fused router: 512 blocks x 256 threads. Block = 16 rows, all 64
// experts. 4 waves: wave w -> expert tile w (16 experts), same 16 rows.
//
// Round-9 theory: rounds 3/6/7/8 all plateaued at ~80us because the HIP
// compiler SINKS register prefetch loads to their consumers (r3 VGPR=56,
// r8 VGPR=104 both below the live-range budget), collapsing the pipeline
// to ~1 outstanding load/CU (Little's law: 1.7 TB/s @ 600cy = 1.7KB in
// flight). Fix = the m97-proven structure, immune to sinking:
//  * x staged RAW FP32 via global_load_lds (no dest reg -> cannot sink),
//    double-buffered, issued BEFORE compute each chunk.
//  * plain __syncthreads() per chunk: its vmcnt(0) drain FORCES both the
//    x DMA and the named-reg B loads to complete one chunk ahead no
//    matter where the compiler schedules the issue.
//  * cvt_split moves AFTER ds_read (fp32 fragments from LDS); 4x per-wave
//    cvt redundancy is fine at VALUBusy 9%.
//  * LDS layout [row][kq^(row&7)] (16B quanta), realized by pre-swizzling
//    the GLOBAL source (rule #21: linear DMA dest + swizzled src + swizzled
//    read) -> conflict-free ds_read_b128.
//  * grid 512 = 2 blocks/CU: one block computes while the other drains.
// ---------------------------------------------------------------------------
__global__ __launch_bounds__(256, 2) void router_kernel(
    const void* __restrict__ xv, const void* __restrict__ wv,
    const void* __restrict__ bv, const void* __restrict__ wsv,
    float* __restrict__ out) {
  __shared__ __align__(16) char xs[2][16384];  // [buf][row 16][kq 64][16B] fp32
  __shared__ float lg[BR][E_DIM + 4];
  __shared__ int   sflag;

  const int tid = threadIdx.x;

  if (tid < 64) {   // dtype probe
    unsigned int v = ((const unsigned int*)xv)[(size_t)tid * 997];
    unsigned int e = (v >> 7) & 0xFFu;
    unsigned long long m = __ballot(e >= 100u && e <= 140u);
    if (tid == 0) sflag = (__popcll(m) > 32) ? 1 : 0;
  }
  __syncthreads();
  const int isbf = sflag;

  const int wave = tid >> 6;            // expert tile 0..3
  const int lane = tid & 63;
  const int lm   = lane & 15;           // A: row-in-tile  B: expert-in-tile
  const int t4   = lane >> 4;           // k sub-slot within 32-wide K step
  const int r0   = blockIdx.x * BR;

  floatx4 acc = {0.f, 0.f, 0.f, 0.f};

  if (!isbf) {
    // ---- staging geometry (global_load_lds, 4 quanta per thread/chunk) ----
    // LDS quantum L = j*256 + tid  ->  row r = j*4 + wave, kq_lds = lane.
    // Source kq = kq_lds ^ (r&7)  (involution; read side applies same XOR).
    // Wave-uniform dest base = xs[buf] + j*4096 + wave*1024 (+lane*16 by HW).
    const char* xbase = (const char*)xv;
    const char* g0 = xbase + (size_t)(r0 + 0*4 + wave) * (D_DIM * 4) +
                     ((lane ^ ((0*4 + wave) & 7)) << 4);
    const char* g1 = xbase + (size_t)(r0 + 1*4 + wave) * (D_DIM * 4) +
                     ((lane ^ ((1*4 + wave) & 7)) << 4);
    const char* g2 = xbase + (size_t)(r0 + 2*4 + wave) * (D_DIM * 4) +
                     ((lane ^ ((2*4 + wave) & 7)) << 4);
    const char* g3 = xbase + (size_t)(r0 + 3*4 + wave) * (D_DIM * 4) +
                     ((lane ^ ((3*4 + wave) & 7)) << 4);
    const int dof = wave << 10;   // wave-uniform dest offset within a j-plane

#define STAGEX(BUF, CH)                                                    \
    {                                                                      \
      char* d = xs[BUF];                                                   \
      gload16(g0 + (size_t)(CH) * 1024, d + 0 * 4096 + dof);               \
      gload16(g1 + (size_t)(CH) * 1024, d + 1 * 4096 + dof);               \
      gload16(g2 + (size_t)(CH) * 1024, d + 2 * 4096 + dof);               \
      gload16(g3 + (size_t)(CH) * 1024, d + 3 * 4096 + dof);               \
    }

    // B fragment base for this wave's expert tile (+lane*16 per fragment)
    const char* wb = (const char*)wsv + (size_t)wave * 2048 + lane * 16;
    // A read: row lm, quanta (2j)^axr and (2j+1)^axr, j = s*4 + t4
    const int ra  = lm << 10;       // row base (1 KB per row)
    const int axr = lm & 7;

    // named B-fragment registers (NO arrays -> stay in VGPRs)
    short8 bh0, bh1, bh2, bh3, bh4, bh5, bh6, bh7;
    short8 bl0, bl1, bl2, bl3, bl4, bl5, bl6, bl7;

#define LDB(K, BASE)                                                       \
    bh##K = *(const short8*)((BASE) + (size_t)(K) * 8192);                 \
    bl##K = *(const short8*)((BASE) + (size_t)(K) * 8192 + 1024);

    // prologue: B frags for chunk 0, x chunk 0 staged to LDS
    LDB(0, wb) LDB(1, wb) LDB(2, wb) LDB(3, wb)
    LDB(4, wb) LDB(5, wb) LDB(6, wb) LDB(7, wb)
    STAGEX(0, 0)
    __syncthreads();   // vmcnt(0)+lgkmcnt(0) drain: stage + B all landed

    for (int i = 0; i < NCH; ++i) {
      // 1) issue next-chunk x DMA first (drained at this chunk's barrier)
      if (i + 1 < NCH) STAGEX((i + 1) & 1, i + 1);
      // 2) compute chunk i; each step reloads its B frag for chunk i+1
      const char* s   = xs[i & 1];
      const char* wbn = wb + (size_t)((i + 1 < NCH) ? i + 1 : i) * (NSTEP * 8192);

#define STEP(K)                                                            \
    {                                                                      \
      const int j2 = ((K) * 4 + t4) * 2;                                   \
      floatx4 p0 = *(const floatx4*)(s + ra + ((j2 ^ axr) << 4));          \
      floatx4 p1 = *(const floatx4*)(s + ra + (((j2 + 1) ^ axr) << 4));    \
      float8 f = {p0[0], p0[1], p0[2], p0[3], p1[0], p1[1], p1[2], p1[3]}; \
      short8 ah, al;                                                       \
      cvt_split(f, ah, al);                                                \
      acc = __builtin_amdgcn_mfma_f32_16x16x32_bf16(ah, bh##K, acc, 0, 0, 0); \
      acc = __builtin_amdgcn_mfma_f32_16x16x32_bf16(ah, bl##K, acc, 0, 0, 0); \
      acc = __builtin_amdgcn_mfma_f32_16x16x32_bf16(al, bh##K, acc, 0, 0, 0); \
      LDB(K, wbn)                                                          \
    }

      STEP(0) STEP(1) STEP(2) STEP(3)
      STEP(4) STEP(5) STEP(6) STEP(7)

      // 3) barrier: drains next-chunk x DMA and all B prefetch loads
      __syncthreads();
    }
#undef STEP
#undef LDB
#undef STAGEX
  } else {
    // bf16 fallback (unexercised; register-direct, no d_ws dependency)
    const short* xp = (const short*)xv + (size_t)(r0 + lm) * D_DIM + t4 * 8;
    const short* wp = (const short*)wv + (size_t)(wave * 16 + lm) * D_DIM + t4 * 8;
    for (int k = 0; k < D_DIM; k += 64) {
      short8 a0 = *(const short8*)(xp + k);
      short8 b0 = *(const short8*)(wp + k);
      short8 a1 = *(const short8*)(xp + k + 32);
      short8 b1 = *(const short8*)(wp + k + 32);
      acc = __builtin_amdgcn_mfma_f32_16x16x32_bf16(a0, b0, acc, 0, 0, 0);
      acc = __builtin_amdgcn_mfma_f32_16x16x32_bf16(a1, b1, acc, 0, 0, 0);
    }
  }

  // C/D layout (m89-verified): col = lane&15 (expert), row = (lane>>4)*4 + reg
  {
    const int col   = wave * 16 + lm;
    const int rbase = t4 << 2;
#pragma unroll
    for (int r = 0; r < 4; ++r) lg[rbase + r][col] = acc[r];
  }
  __syncthreads();

  if (tid < BR) {
    const int row = tid;
    float m1 = -3.4e38f, m2 = -3.4e38f;
    int   i1 = 0, i2 = 0;
    for (int e = 0; e < E_DIM; ++e) {
      float be = isbf ? __bfloat162float(((const __hip_bfloat16*)bv)[e])
                      : ((const float*)bv)[e];
      float l = lg[row][e] + be;
      if (l > m1)      { m2 = m1; i2 = i1; m1 = l; i1 = e; }
      else if (l > m2) { m2 = l;  i2 = e; }
    }
    float s = 0.f;
    for (int e = 0; e < E_DIM; ++e) {
      float be = isbf ? __bfloat162float(((const __hip_bfloat16*)bv)[e])
                      : ((const float*)bv)[e];
      s += expf(lg[row][e] + be - m1);
    }
    const int gr = r0 + row;
    // outputs concatenated flat: [N*2 indices][N*2 weights], all as float32
    out[2 * gr]                  = (float)i1;
    out[2 * gr + 1]              = (float)i2;
    out[2 * N_ROWS + 2 * gr]     = 1.0f / s;                 // exp(m1-m1)/s
    out[2 * N_ROWS + 2 * gr + 1] = expf(m2 - m1) / s;
  }
}

extern "C" void kernel_launch(void* const* d_in, const int* in_sizes, int n_in,
                              void* d_out, int out_size, void* d_ws, size_t ws_size,
                              hipStream_t stream) {
  (void)in_sizes; (void)n_in; (void)out_size; (void)ws_size;
  // prep_w writes 1 MB of fragment-ordered split-bf16 W into d_ws;
  // same-stream ordering guarantees completion before router_kernel.
  prep_w<<<dim3(64), dim3(512), 0, stream>>>(d_in[0], d_in[1], d_ws);
  router_kernel<<<dim3(N_ROWS / BR), dim3(256), 0, stream>>>(
      d_in[0], d_in[1], d_in[2], d_ws, (float*)d_out);
}